// Round 10
// baseline (305.712 us; speedup 1.0000x reference)
//
#include <hip/hip_runtime.h>

// B=4, T=4096, E=204, H=64, fp32 in/out. Causal single-head attention.
#define TSEQ   4096
#define NB     4
#define EMB    204
#define HD     64
#define WK     224    // padded K dim for projection (204 -> 7*32)
#define XSTR   232    // x LDS row stride (shorts)
#define KTILE  64     // keys per flash tile

typedef __attribute__((ext_vector_type(8))) short bf16x8;
typedef __attribute__((ext_vector_type(4))) float f32x4;
typedef __attribute__((ext_vector_type(16))) float f32x16;
typedef __attribute__((ext_vector_type(4))) unsigned u32x4;

__device__ __forceinline__ short f2bf(float f) {
    unsigned u = __float_as_uint(f);
    return (short)((u + 0x7fffu + ((u >> 16) & 1u)) >> 16);  // RNE
}

// ---------------------------------------------------------------------------
// Prep: W transpose->bf16 (Wt [3][64][224]) + zero split-K ticket flags.
// ---------------------------------------------------------------------------
__global__ __launch_bounds__(256) void prep_kernel(
    const float* __restrict__ Wq,
    const float* __restrict__ Wk,
    const float* __restrict__ Wv,
    short* __restrict__ Wt,
    int* __restrict__ flags)      // [NB*32] tickets, zeroed every launch
{
    int f = blockIdx.x * 256 + threadIdx.x;
    if (f < 3 * HD * WK) {
        int e   = f % WK;
        int h   = (f / WK) % HD;
        int mat = f / (WK * HD);
        const float* W = (mat == 0) ? Wq : (mat == 1) ? Wk : Wv;
        float v = (e < EMB) ? W[e * HD + h] : 0.f;
        Wt[f] = f2bf(v);
    }
    if (blockIdx.x == 0 && threadIdx.x < NB * 32)
        flags[threadIdx.x] = 0;
}

// ---------------------------------------------------------------------------
// QKV projection: 1024 blocks x 192 thr (3 waves). Block = 16 x-rows.
// Wave w computes matrix w (28 MFMA). q is PRE-SCALED by log2(e)/sqrt(204)
// so the flash kernel can use native v_exp_f32 (2^x) directly.
// q,k -> [row][64] bf16; v -> vT [b][hd][4096] bf16.  (v5 epilogue: the v8
// LDS-transpose variant measured neutral-to-worse; scatter stores kept.)
// ---------------------------------------------------------------------------
__global__ __launch_bounds__(192) void qkv_mfma_kernel(
    const float* __restrict__ x,
    const short* __restrict__ Wt,
    short* __restrict__ qg,
    short* __restrict__ kg,
    short* __restrict__ vtg)
{
    __shared__ __align__(16) short xs[16 * XSTR];

    const int t    = threadIdx.x;
    const int lane = t & 63;
    const int w    = t >> 6;          // 0..2 = matrix id
    const int l15  = lane & 15;
    const int quad = lane >> 4;
    const long long rowb = (long long)blockIdx.x * 16;

    for (int c = t; c < 816; c += 192) {
        int r = c / 51, c4 = c % 51;
        float4 xv = *(const float4*)(x + (rowb + r) * EMB + c4 * 4);
        unsigned p0 = (unsigned)(unsigned short)f2bf(xv.x)
                    | ((unsigned)(unsigned short)f2bf(xv.y) << 16);
        unsigned p1 = (unsigned)(unsigned short)f2bf(xv.z)
                    | ((unsigned)(unsigned short)f2bf(xv.w) << 16);
        uint2 pk; pk.x = p0; pk.y = p1;
        *(uint2*)(&xs[r * XSTR + c4 * 4]) = pk;
    }
    for (int c = t; c < 16 * 28; c += 192) {       // zero pad cols 204..231
        int r = c / 28, cc = c % 28;
        xs[r * XSTR + EMB + cc] = 0;
    }
    __syncthreads();

    f32x4 acc[4];
#pragma unroll
    for (int nt = 0; nt < 4; ++nt) acc[nt] = (f32x4){0.f, 0.f, 0.f, 0.f};

    const short* Wb = Wt + (size_t)w * HD * WK;
#pragma unroll
    for (int ks = 0; ks < 7; ++ks) {
        bf16x8 af = *(const bf16x8*)(&xs[l15 * XSTR + ks * 32 + quad * 8]);
#pragma unroll
        for (int nt = 0; nt < 4; ++nt) {
            bf16x8 bfr = *(const bf16x8*)(Wb + (size_t)(nt * 16 + l15) * WK
                                          + ks * 32 + quad * 8);
            acc[nt] = __builtin_amdgcn_mfma_f32_16x16x32_bf16(af, bfr, acc[nt], 0, 0, 0);
        }
    }

    // scale = log2(e) / sqrt(204), folded into q (flash uses exp2)
    const float scale = 0.101008857f;
    if (w == 0) {
#pragma unroll
        for (int r = 0; r < 4; ++r) {
            long long grow = rowb + quad * 4 + r;
#pragma unroll
            for (int nt = 0; nt < 4; ++nt)
                qg[grow * HD + nt * 16 + l15] = f2bf(acc[nt][r] * scale);
        }
    } else if (w == 1) {
#pragma unroll
        for (int r = 0; r < 4; ++r) {
            long long grow = rowb + quad * 4 + r;
#pragma unroll
            for (int nt = 0; nt < 4; ++nt)
                kg[grow * HD + nt * 16 + l15] = f2bf(acc[nt][r]);
        }
    } else {
#pragma unroll
        for (int r = 0; r < 4; ++r) {
            long long grow = rowb + quad * 4 + r;
            int bb = (int)(grow >> 12);
            int tt = (int)(grow & 4095);
#pragma unroll
            for (int nt = 0; nt < 4; ++nt)
                vtg[((long long)bb * HD + nt * 16 + l15) * TSEQ + tt] = f2bf(acc[nt][r]);
        }
    }
}

// ---------------------------------------------------------------------------
// Flash attention v9 = v5 core (proven) + in-flash split-K fixup, replacing
// the finalize kernel. Key difference from failed v6: __launch_bounds__
// stays (256,4) -> VGPR 64, no K-loop spills (v6's (256,5)/VGPR48 was the
// 5x regression; FETCH/WRITE spill signature).
//
// Compute core (unchanged, verified): swapped-operand 32x32x16 MFMA
// (S^T = K Q^T), in-register softmax via exp2 + v_cvt_pk_bf16_f32 +
// v_permlane32_swap_b32, K/V double-buffered global_load_lds with XOR-
// swizzled global source, 1 barrier/tile, smax=8 stream-K.
// Epilogue: s==1 blocks normalize + write out directly. s>1 blocks write
// a private partial segment, __threadfence (release) + ticket atomicAdd;
// last block of each q-tile acquires and sums the s segments (L2/L3-hot),
// then writes out. No separate finalize kernel.
// ---------------------------------------------------------------------------
__global__ __launch_bounds__(256, 4) void flash_mfma_kernel(
    const short* __restrict__ qg,    // bf16 [NB*T][64], pre-scaled
    const short* __restrict__ kg,    // bf16 [NB*T][64]
    const short* __restrict__ vtg,   // bf16 [NB][64][T]
    float* __restrict__ oparts,      // fp32 [NB][NSEG][8192]
    float* __restrict__ lparts,      // fp32 [NB][NSEG][128]
    float* __restrict__ out,         // fp32 [NB*T][64]
    int* __restrict__ flags,         // [NB*32] tickets (zeroed by prep)
    int NSEGk, int smax)
{
    __shared__ __align__(16) short Ks[2][KTILE * HD];   // 2 x 8 KB, linear
    __shared__ __align__(16) short Vt[2][HD * KTILE];   // 2 x 8 KB, linear

    const int t    = threadIdx.x;
    const int lane = t & 63;
    const int w    = t >> 6;
    const int l31  = lane & 31;
    const int hi   = lane >> 5;
    const int wq   = w * 32;              // wave's q-row offset in block

    const int b = blockIdx.y;
    const int p = NSEGk - 1 - (int)blockIdx.x;  // biggest qt3 dispatched first

    // Decode p -> (qt3, split): s(qt3) = min(smax,(qt3+2)>>1), prefix walk.
    int qt3 = 0, base = 0;
    for (;; ++qt3) {
        int sg = (qt3 + 2) >> 1;
        if (sg > smax) sg = smax;
        if (p < base + sg) break;
        base += sg;
    }
    int s = (qt3 + 2) >> 1;
    if (s > smax) s = smax;
    const int split  = p - base;
    const int ntiles = 2 * qt3 + 2;
    const int chunk  = (ntiles + s - 1) / s;
    const int kt0    = split * chunk;               // may be >= kt1 (empty)
    const int kt1    = min(ntiles, kt0 + chunk);

    const int qbase = qt3 * 128;
    const long long rowb = (long long)b * TSEQ;
    const int qA = qbase + wq + l31;      // this lane's q row (within batch)

    // Q B-fragments (pre-scaled): aq[c] = qg[qA][c*16 + hi*8 .. +7]
    bf16x8 aq[4];
#pragma unroll
    for (int c = 0; c < 4; ++c)
        aq[c] = *(const bf16x8*)(qg + (rowb + qA) * HD + c * 16 + hi * 8);

    f32x16 Oacc[2];
#pragma unroll
    for (int hg = 0; hg < 2; ++hg)
#pragma unroll
        for (int r = 0; r < 16; ++r) Oacc[hg][r] = 0.f;
    float lsum = 0.f;

    // Async stage of tile KT into buffer BUF. Each wave issues 2 K + 2 V
    // global_load_lds (1 KB each: 8 rows x 128 B). LDS dest linear; global
    // src chunk = lds_chunk ^ (row&7)  (both tiles are 64 rows x 8 chunks).
#define STAGE(BUF, KT) do {                                                   \
        const int k0s = (KT) * KTILE;                                         \
        _Pragma("unroll")                                                     \
        for (int j = 0; j < 2; ++j) {                                         \
            const int rr = (w * 2 + j) * 8 + (lane >> 3);                     \
            const int cc = (lane & 7) ^ (rr & 7);                             \
            const short* srcK = kg + (rowb + k0s + rr) * HD + cc * 8;         \
            __builtin_amdgcn_global_load_lds(                                 \
                (const __attribute__((address_space(1))) void*)srcK,          \
                (__attribute__((address_space(3))) void*)&Ks[BUF][(w * 2 + j) * 512], \
                16, 0, 0);                                                    \
            const short* srcV = vtg + ((long long)b * HD + rr) * TSEQ + k0s + cc * 8; \
            __builtin_amdgcn_global_load_lds(                                 \
                (const __attribute__((address_space(1))) void*)srcV,          \
                (__attribute__((address_space(3))) void*)&Vt[BUF][(w * 2 + j) * 512], \
                16, 0, 0);                                                    \
        }                                                                     \
    } while (0)

    int cur = 0;
    STAGE(0, kt0);
    __syncthreads();   // drain staging (vmcnt) + sync

    for (int kt = kt0; kt < kt1; ++kt) {
        const int k0 = kt * KTILE;
        if (kt + 1 < kt1) STAGE(cur ^ 1, kt + 1);   // async prefetch next

        const short* ksb = Ks[cur];
        const short* vsb = Vt[cur];
        const bool act  = (k0 <= qbase + wq + 31);  // wave has allowed keys
        const bool full = (k0 + 63 <= qbase + wq);  // no masking needed

        if (act) {
            // ---- S^T = K Q^T, then in-register softmax -> packed P^T ----
            unsigned cd[2][8];
#pragma unroll
            for (int kg2 = 0; kg2 < 2; ++kg2) {
                f32x16 S;
#pragma unroll
                for (int r = 0; r < 16; ++r) S[r] = 0.f;
#pragma unroll
                for (int c = 0; c < 4; ++c) {
                    bf16x8 kf = *(const bf16x8*)(ksb + (kg2 * 32 + l31) * HD
                                   + (((2 * c + hi) ^ (l31 & 7)) * 8));
                    S = __builtin_amdgcn_mfma_f32_32x32x16_bf16(kf, aq[c], S, 0, 0, 0);
                }
                const int jb = k0 + kg2 * 32 + 4 * hi;   // key base for this lane
#pragma unroll
                for (int g = 0; g < 8; ++g) {
                    float e0 = __builtin_amdgcn_exp2f(S[2 * g]);
                    float e1 = __builtin_amdgcn_exp2f(S[2 * g + 1]);
                    if (!full) {
                        const int j0 = jb + 8 * (g >> 1) + 2 * (g & 1);
                        if (j0     > qA) e0 = 0.f;
                        if (j0 + 1 > qA) e1 = 0.f;
                    }
                    lsum += e0 + e1;
                    asm("v_cvt_pk_bf16_f32 %0, %1, %2"
                        : "=v"(cd[kg2][g]) : "v"(e0), "v"(e1));
                }
            }

            // ---- O^T += V^T P^T : permlane32_swap builds P^T B-frags ----
#pragma unroll
            for (int kc = 0; kc < 4; ++kc) {
                unsigned u0 = cd[kc >> 1][4 * (kc & 1) + 0];
                unsigned u1 = cd[kc >> 1][4 * (kc & 1) + 1];
                unsigned u2 = cd[kc >> 1][4 * (kc & 1) + 2];
                unsigned u3 = cd[kc >> 1][4 * (kc & 1) + 3];
                asm("v_permlane32_swap_b32 %0, %1" : "+v"(u0), "+v"(u2));
                asm("v_permlane32_swap_b32 %0, %1" : "+v"(u1), "+v"(u3));
                u32x4 pk = {u0, u1, u2, u3};
                bf16x8 pb = __builtin_bit_cast(bf16x8, pk);
#pragma unroll
                for (int hg = 0; hg < 2; ++hg) {
                    bf16x8 vf = *(const bf16x8*)(vsb + (hg * 32 + l31) * HD
                                   + (((2 * kc + hi) ^ (l31 & 7)) * 8));
                    Oacc[hg] = __builtin_amdgcn_mfma_f32_32x32x16_bf16(vf, pb, Oacc[hg], 0, 0, 0);
                }
            }
        }

        __syncthreads();   // staging of next tile complete; all reads done
        cur ^= 1;
    }

    // l: combine the two 32-key halves (lanes l, l^32).
    lsum += __shfl_xor(lsum, 32, 64);

    if (s == 1) {
        // Unsplit q-tile: normalize in-register, write final out directly.
        const float inv = 1.0f / lsum;
        float* orow = out + (rowb + qA) * HD;
#pragma unroll
        for (int hg = 0; hg < 2; ++hg)
#pragma unroll
            for (int rq = 0; rq < 4; ++rq) {
                float4 v = make_float4(Oacc[hg][4 * rq + 0] * inv,
                                       Oacc[hg][4 * rq + 1] * inv,
                                       Oacc[hg][4 * rq + 2] * inv,
                                       Oacc[hg][4 * rq + 3] * inv);
                *(float4*)(orow + hg * 32 + hi * 4 + rq * 8) = v;
            }
        return;
    }

    // ---- Split path: stream partial (O,l) to this block's private segment.
    float* optr = oparts + ((size_t)b * NSEGk + p) * 8192
                + (size_t)w * 2048 + (size_t)lane * 32;
#pragma unroll
    for (int hg = 0; hg < 2; ++hg)
#pragma unroll
        for (int rq = 0; rq < 4; ++rq) {
            float4 v = make_float4(Oacc[hg][4 * rq + 0], Oacc[hg][4 * rq + 1],
                                   Oacc[hg][4 * rq + 2], Oacc[hg][4 * rq + 3]);
            *(float4*)(optr + hg * 16 + rq * 4) = v;
        }
    if (hi == 0)
        lparts[((size_t)b * NSEGk + p) * 128 + w * 32 + l31] = lsum;

    // Release this block's stores, then take a ticket.
    __threadfence();
    __syncthreads();
    volatile int* donep = (volatile int*)&Ks[0][0];
    if (t == 0) {
        int old = atomicAdd(&flags[b * 32 + qt3], 1);
        *donep = (old == s - 1) ? 1 : 0;
    }
    __syncthreads();
    if (*donep == 0) return;

    // ---- Fixup (last block of this q-tile): sum s segments, write out.
    __threadfence();   // acquire: see other blocks' partials
    const float* osegs = oparts + ((size_t)b * NSEGk + base) * 8192;
    const float* lsegs = lparts + ((size_t)b * NSEGk + base) * 128;

    float* linv = (float*)&Vt[0][0];   // 128 floats; LDS tiles dead now
    if (t < 128) {
        float a = 0.f;
        for (int k = 0; k < s; ++k) a += lsegs[(size_t)k * 128 + t];
        linv[t] = 1.0f / a;
    }
    __syncthreads();

    for (int i = t * 4; i < 8192; i += 1024) {
        float4 a = *(const float4*)(osegs + i);
        for (int k = 1; k < s; ++k) {
            float4 v = *(const float4*)(osegs + (size_t)k * 8192 + i);
            a.x += v.x; a.y += v.y; a.z += v.z; a.w += v.w;
        }
        const int wseg  = i >> 11;
        const int lane2 = (i >> 5) & 63;
        const int hg2   = (i >> 4) & 1;
        const int rq2   = (i >> 2) & 3;
        const int lrow  = wseg * 32 + (lane2 & 31);
        const float inv = linv[lrow];
        a.x *= inv; a.y *= inv; a.z *= inv; a.w *= inv;
        const int col = hg2 * 32 + (lane2 >> 5) * 4 + rq2 * 8;
        *(float4*)(out + (rowb + qbase + lrow) * HD + col) = a;
    }
#undef STAGE
}

// ---------------------------------------------------------------------------
extern "C" void kernel_launch(void* const* d_in, const int* in_sizes, int n_in,
                              void* d_out, int out_size, void* d_ws, size_t ws_size,
                              hipStream_t stream)
{
    const float* x  = (const float*)d_in[0];
    const float* Wq = (const float*)d_in[1];
    const float* Wk = (const float*)d_in[2];
    const float* Wv = (const float*)d_in[3];

    const size_t nrows = (size_t)NB * TSEQ;

    // Split depth from workspace budget. smax=8 (v5-proven): 800 blocks.
    const size_t fixed_bytes = 3 * nrows * HD * 2 + (size_t)3 * HD * WK * 2;
    int smax = 1, NSEG = 32;
    const int cands[3] = {8, 4, 2};
    for (int i = 0; i < 3; ++i) {
        int sm = cands[i], ns = 0;
        for (int q = 0; q < 32; ++q) {
            int sg = (q + 2) >> 1;
            if (sg > sm) sg = sm;
            ns += sg;
        }
        size_t need = fixed_bytes + (size_t)NB * ns * (8192 + 128) * 4
                    + (size_t)NB * 32 * 4;
        if (need <= ws_size) { smax = sm; NSEG = ns; break; }
    }

    short* qg  = (short*)d_ws;                 // bf16 [nrows][64]   2 MB
    short* kg  = qg + nrows * HD;              // bf16 [nrows][64]   2 MB
    short* vtg = kg + nrows * HD;              // bf16 [NB][64][T]   2 MB
    short* Wt  = vtg + nrows * HD;             // bf16 [3][64][224]  84 KB
    float* oparts = (float*)(Wt + 3 * HD * WK);// fp32 [NB][NSEG][8192]
    float* lparts = oparts + (size_t)NB * NSEG * 8192; // fp32 [NB][NSEG][128]
    int*   flags  = (int*)(lparts + (size_t)NB * NSEG * 128);   // [NB*32]
    float* outp = (float*)d_out;

    prep_kernel<<<dim3(168), dim3(256), 0, stream>>>(Wq, Wk, Wv, Wt, flags);
    qkv_mfma_kernel<<<dim3(1024), dim3(192), 0, stream>>>(x, Wt, qg, kg, vtg);
    flash_mfma_kernel<<<dim3(NSEG, NB), dim3(256), 0, stream>>>(qg, kg, vtg,
                                                               oparts, lparts,
                                                               outp, flags,
                                                               NSEG, smax);
}

// Round 11
// 110.075 us; speedup vs baseline: 2.7773x; 2.7773x over previous
//
#include <hip/hip_runtime.h>

// B=4, T=4096, E=204, H=64, fp32 in/out. Causal single-head attention.
#define TSEQ   4096
#define NB     4
#define EMB    204
#define HD     64
#define WK     224    // padded K dim for projection (204 -> 7*32)
#define XSTR   232    // x LDS row stride (shorts)
#define KTILE  64     // keys per flash tile

typedef __attribute__((ext_vector_type(8))) short bf16x8;
typedef __attribute__((ext_vector_type(4))) float f32x4;
typedef __attribute__((ext_vector_type(16))) float f32x16;
typedef __attribute__((ext_vector_type(4))) unsigned u32x4;

__device__ __forceinline__ short f2bf(float f) {
    unsigned u = __float_as_uint(f);
    return (short)((u + 0x7fffu + ((u >> 16) & 1u)) >> 16);  // RNE
}

// ---------------------------------------------------------------------------
// Prep: W transpose->bf16 (Wt [3][64][224]). No zero-init needed anywhere:
// flash writes every partial segment unconditionally.
// ---------------------------------------------------------------------------
__global__ __launch_bounds__(256) void prep_kernel(
    const float* __restrict__ Wq,
    const float* __restrict__ Wk,
    const float* __restrict__ Wv,
    short* __restrict__ Wt)
{
    int f = blockIdx.x * 256 + threadIdx.x;
    if (f < 3 * HD * WK) {
        int e   = f % WK;
        int h   = (f / WK) % HD;
        int mat = f / (WK * HD);
        const float* W = (mat == 0) ? Wq : (mat == 1) ? Wk : Wv;
        float v = (e < EMB) ? W[e * HD + h] : 0.f;
        Wt[f] = f2bf(v);
    }
}

// ---------------------------------------------------------------------------
// QKV projection v2: 512 blocks x 192 thr (3 waves). Block = 32 x-rows
// (was 16): halves block count/prologues and doubles W-fragment reuse
// (each bfr feeds 2 MFMA). Wave w computes matrix w (56 MFMA over 2
// 16-row tiles). q is PRE-SCALED by log2(e)/sqrt(204) for exp2 in flash.
// q,k -> [row][64] bf16; v -> vT [b][hd][4096] bf16 (v5 scatter epilogue;
// the v8 LDS-transpose variant measured neutral).
// ---------------------------------------------------------------------------
__global__ __launch_bounds__(192) void qkv_mfma_kernel(
    const float* __restrict__ x,
    const short* __restrict__ Wt,
    short* __restrict__ qg,
    short* __restrict__ kg,
    short* __restrict__ vtg)
{
    __shared__ __align__(16) short xs[32 * XSTR];   // 14848 B

    const int t    = threadIdx.x;
    const int lane = t & 63;
    const int w    = t >> 6;          // 0..2 = matrix id
    const int l15  = lane & 15;
    const int quad = lane >> 4;
    const long long rowb = (long long)blockIdx.x * 32;

    // Stage x tile (32 x 204 fp32 -> bf16): 1632 float4 chunks.
    for (int c = t; c < 1632; c += 192) {
        int r = c / 51, c4 = c % 51;
        float4 xv = *(const float4*)(x + (rowb + r) * EMB + c4 * 4);
        unsigned p0 = (unsigned)(unsigned short)f2bf(xv.x)
                    | ((unsigned)(unsigned short)f2bf(xv.y) << 16);
        unsigned p1 = (unsigned)(unsigned short)f2bf(xv.z)
                    | ((unsigned)(unsigned short)f2bf(xv.w) << 16);
        uint2 pk; pk.x = p0; pk.y = p1;
        *(uint2*)(&xs[r * XSTR + c4 * 4]) = pk;
    }
    for (int c = t; c < 32 * 28; c += 192) {       // zero pad cols 204..231
        int r = c / 28, cc = c % 28;
        xs[r * XSTR + EMB + cc] = 0;
    }
    __syncthreads();

    f32x4 acc[2][4];
#pragma unroll
    for (int rt = 0; rt < 2; ++rt)
#pragma unroll
        for (int nt = 0; nt < 4; ++nt) acc[rt][nt] = (f32x4){0.f, 0.f, 0.f, 0.f};

    const short* Wb = Wt + (size_t)w * HD * WK;
#pragma unroll
    for (int ks = 0; ks < 7; ++ks) {
        bf16x8 af[2];
#pragma unroll
        for (int rt = 0; rt < 2; ++rt)
            af[rt] = *(const bf16x8*)(&xs[(rt * 16 + l15) * XSTR + ks * 32 + quad * 8]);
#pragma unroll
        for (int nt = 0; nt < 4; ++nt) {
            bf16x8 bfr = *(const bf16x8*)(Wb + (size_t)(nt * 16 + l15) * WK
                                          + ks * 32 + quad * 8);
#pragma unroll
            for (int rt = 0; rt < 2; ++rt)
                acc[rt][nt] = __builtin_amdgcn_mfma_f32_16x16x32_bf16(af[rt], bfr, acc[rt][nt], 0, 0, 0);
        }
    }

    // scale = log2(e) / sqrt(204), folded into q (flash uses exp2)
    const float scale = 0.101008857f;
#pragma unroll
    for (int rt = 0; rt < 2; ++rt) {
        if (w == 0) {
#pragma unroll
            for (int r = 0; r < 4; ++r) {
                long long grow = rowb + rt * 16 + quad * 4 + r;
#pragma unroll
                for (int nt = 0; nt < 4; ++nt)
                    qg[grow * HD + nt * 16 + l15] = f2bf(acc[rt][nt][r] * scale);
            }
        } else if (w == 1) {
#pragma unroll
            for (int r = 0; r < 4; ++r) {
                long long grow = rowb + rt * 16 + quad * 4 + r;
#pragma unroll
                for (int nt = 0; nt < 4; ++nt)
                    kg[grow * HD + nt * 16 + l15] = f2bf(acc[rt][nt][r]);
            }
        } else {
#pragma unroll
            for (int r = 0; r < 4; ++r) {
                long long grow = rowb + rt * 16 + quad * 4 + r;
                int bb = (int)(grow >> 12);
                int tt = (int)(grow & 4095);
#pragma unroll
                for (int nt = 0; nt < 4; ++nt)
                    vtg[((long long)bb * HD + nt * 16 + l15) * TSEQ + tt] = f2bf(acc[rt][nt][r]);
            }
        }
    }
}

// ---------------------------------------------------------------------------
// Flash attention: v5 core, UNCHANGED (proven 109.9us config).
// Post-mortems: (256,5) VGPR cap -> spills (v6); smax=16 -> partial-traffic
// loss (v7); in-flash fixup w/ threadfence+ticket -> catastrophic even
// without spills (v9: 253us, fence/L2-writeback path). Flash is frozen.
//
// Core: swapped-operand 32x32x16 MFMA (S^T = K Q^T: C layout col=lane&31,
// row=(r&3)+8*(r>>2)+4*hi), in-register softmax via exp2 (q pre-scaled by
// log2e) + v_cvt_pk_bf16_f32 + v_permlane32_swap_b32 -> PV B-frags, zero
// P-LDS; K/V double-buffered global_load_lds (linear LDS dest, XOR-swizzled
// per-lane global src, same XOR on read -> conflict-free ds_read_b128);
// 1 barrier/tile; smax=8 stream-K; partials to private segments; NO atomics.
// ---------------------------------------------------------------------------
__global__ __launch_bounds__(256, 4) void flash_mfma_kernel(
    const short* __restrict__ qg,    // bf16 [NB*T][64], pre-scaled
    const short* __restrict__ kg,    // bf16 [NB*T][64]
    const short* __restrict__ vtg,   // bf16 [NB][64][T]
    float* __restrict__ oparts,      // fp32 [NB][NSEG][8192]
    float* __restrict__ lparts,      // fp32 [NB][NSEG][128]
    int NSEGk, int smax)
{
    __shared__ __align__(16) short Ks[2][KTILE * HD];   // 2 x 8 KB, linear
    __shared__ __align__(16) short Vt[2][HD * KTILE];   // 2 x 8 KB, linear

    const int t    = threadIdx.x;
    const int lane = t & 63;
    const int w    = t >> 6;
    const int l31  = lane & 31;
    const int hi   = lane >> 5;
    const int wq   = w * 32;              // wave's q-row offset in block

    const int b = blockIdx.y;
    const int p = NSEGk - 1 - (int)blockIdx.x;  // biggest qt3 dispatched first

    // Decode p -> (qt3, split): s(qt3) = min(smax,(qt3+2)>>1), prefix walk.
    int qt3 = 0, base = 0;
    for (;; ++qt3) {
        int sg = (qt3 + 2) >> 1;
        if (sg > smax) sg = smax;
        if (p < base + sg) break;
        base += sg;
    }
    int s = (qt3 + 2) >> 1;
    if (s > smax) s = smax;
    const int split  = p - base;
    const int ntiles = 2 * qt3 + 2;
    const int chunk  = (ntiles + s - 1) / s;
    const int kt0    = split * chunk;
    const int kt1    = min(ntiles, kt0 + chunk);

    const int qbase = qt3 * 128;
    const long long rowb = (long long)b * TSEQ;
    const int qA = qbase + wq + l31;      // this lane's q row (within batch)

    // Q B-fragments (pre-scaled): aq[c] = qg[qA][c*16 + hi*8 .. +7]
    bf16x8 aq[4];
#pragma unroll
    for (int c = 0; c < 4; ++c)
        aq[c] = *(const bf16x8*)(qg + (rowb + qA) * HD + c * 16 + hi * 8);

    f32x16 Oacc[2];
#pragma unroll
    for (int hg = 0; hg < 2; ++hg)
#pragma unroll
        for (int r = 0; r < 16; ++r) Oacc[hg][r] = 0.f;
    float lsum = 0.f;

    // Async stage of tile KT into buffer BUF. Each wave issues 2 K + 2 V
    // global_load_lds (1 KB each: 8 rows x 128 B). LDS dest linear; global
    // src chunk = lds_chunk ^ (row&7)  (both tiles are 64 rows x 8 chunks).
#define STAGE(BUF, KT) do {                                                   \
        const int k0s = (KT) * KTILE;                                         \
        _Pragma("unroll")                                                     \
        for (int j = 0; j < 2; ++j) {                                         \
            const int rr = (w * 2 + j) * 8 + (lane >> 3);                     \
            const int cc = (lane & 7) ^ (rr & 7);                             \
            const short* srcK = kg + (rowb + k0s + rr) * HD + cc * 8;         \
            __builtin_amdgcn_global_load_lds(                                 \
                (const __attribute__((address_space(1))) void*)srcK,          \
                (__attribute__((address_space(3))) void*)&Ks[BUF][(w * 2 + j) * 512], \
                16, 0, 0);                                                    \
            const short* srcV = vtg + ((long long)b * HD + rr) * TSEQ + k0s + cc * 8; \
            __builtin_amdgcn_global_load_lds(                                 \
                (const __attribute__((address_space(1))) void*)srcV,          \
                (__attribute__((address_space(3))) void*)&Vt[BUF][(w * 2 + j) * 512], \
                16, 0, 0);                                                    \
        }                                                                     \
    } while (0)

    int cur = 0;
    STAGE(0, kt0);
    __syncthreads();   // drain staging (vmcnt) + sync

    for (int kt = kt0; kt < kt1; ++kt) {
        const int k0 = kt * KTILE;
        if (kt + 1 < kt1) STAGE(cur ^ 1, kt + 1);   // async prefetch next

        const short* ksb = Ks[cur];
        const short* vsb = Vt[cur];
        const bool act  = (k0 <= qbase + wq + 31);  // wave has allowed keys
        const bool full = (k0 + 63 <= qbase + wq);  // no masking needed

        if (act) {
            // ---- S^T = K Q^T, then in-register softmax -> packed P^T ----
            unsigned cd[2][8];
#pragma unroll
            for (int kg2 = 0; kg2 < 2; ++kg2) {
                f32x16 S;
#pragma unroll
                for (int r = 0; r < 16; ++r) S[r] = 0.f;
#pragma unroll
                for (int c = 0; c < 4; ++c) {
                    bf16x8 kf = *(const bf16x8*)(ksb + (kg2 * 32 + l31) * HD
                                   + (((2 * c + hi) ^ (l31 & 7)) * 8));
                    S = __builtin_amdgcn_mfma_f32_32x32x16_bf16(kf, aq[c], S, 0, 0, 0);
                }
                const int jb = k0 + kg2 * 32 + 4 * hi;   // key base for this lane
#pragma unroll
                for (int g = 0; g < 8; ++g) {
                    float e0 = __builtin_amdgcn_exp2f(S[2 * g]);
                    float e1 = __builtin_amdgcn_exp2f(S[2 * g + 1]);
                    if (!full) {
                        const int j0 = jb + 8 * (g >> 1) + 2 * (g & 1);
                        if (j0     > qA) e0 = 0.f;
                        if (j0 + 1 > qA) e1 = 0.f;
                    }
                    lsum += e0 + e1;
                    asm("v_cvt_pk_bf16_f32 %0, %1, %2"
                        : "=v"(cd[kg2][g]) : "v"(e0), "v"(e1));
                }
            }

            // ---- O^T += V^T P^T : permlane32_swap builds P^T B-frags ----
#pragma unroll
            for (int kc = 0; kc < 4; ++kc) {
                unsigned u0 = cd[kc >> 1][4 * (kc & 1) + 0];
                unsigned u1 = cd[kc >> 1][4 * (kc & 1) + 1];
                unsigned u2 = cd[kc >> 1][4 * (kc & 1) + 2];
                unsigned u3 = cd[kc >> 1][4 * (kc & 1) + 3];
                asm("v_permlane32_swap_b32 %0, %1" : "+v"(u0), "+v"(u2));
                asm("v_permlane32_swap_b32 %0, %1" : "+v"(u1), "+v"(u3));
                u32x4 pk = {u0, u1, u2, u3};
                bf16x8 pb = __builtin_bit_cast(bf16x8, pk);
#pragma unroll
                for (int hg = 0; hg < 2; ++hg) {
                    bf16x8 vf = *(const bf16x8*)(vsb + (hg * 32 + l31) * HD
                                   + (((2 * kc + hi) ^ (l31 & 7)) * 8));
                    Oacc[hg] = __builtin_amdgcn_mfma_f32_32x32x16_bf16(vf, pb, Oacc[hg], 0, 0, 0);
                }
            }
        }

        __syncthreads();   // staging of next tile complete; all reads done
        cur ^= 1;
    }

    // ---- Epilogue: stream partial (O, l) to this block's private segment.
    // Layout: oparts[b][p][w*2048 + lane*32 + hg*16 + r]  (coalesced x4).
    float* optr = oparts + ((size_t)b * NSEGk + p) * 8192
                + (size_t)w * 2048 + (size_t)lane * 32;
#pragma unroll
    for (int hg = 0; hg < 2; ++hg)
#pragma unroll
        for (int rq = 0; rq < 4; ++rq) {
            float4 v = make_float4(Oacc[hg][4 * rq + 0], Oacc[hg][4 * rq + 1],
                                   Oacc[hg][4 * rq + 2], Oacc[hg][4 * rq + 3]);
            *(float4*)(optr + hg * 16 + rq * 4) = v;
        }

    lsum += __shfl_xor(lsum, 32, 64);
    if (hi == 0)
        lparts[((size_t)b * NSEGk + p) * 128 + w * 32 + l31] = lsum;
#undef STAGE
}

// ---------------------------------------------------------------------------
// Finalize: out[row][col] = sum_s opart / sum_s lpart. 1024 x 256, 16 rows/blk.
// col -> fragment index: hi=(col>>2)&1, hg=col>>5, r=(col&3)+4*((col&31)>>3).
// ---------------------------------------------------------------------------
__global__ __launch_bounds__(256) void finalize_kernel(
    const float* __restrict__ oparts,
    const float* __restrict__ lparts,
    float* __restrict__ out,
    int NSEGk, int smax)
{
    const int row = blockIdx.x * 16 + (threadIdx.x >> 4);
    const int c0  = (threadIdx.x & 15) * 4;
    const int b = row >> 12, rowin = row & 4095;
    const int qt3 = rowin >> 7, w = (rowin >> 5) & 3, l31 = rowin & 31;

    int segbase = 0;
    for (int j = 0; j < qt3; ++j) {
        int sg = (j + 2) >> 1;
        if (sg > smax) sg = smax;
        segbase += sg;
    }
    int s = (qt3 + 2) >> 1;
    if (s > smax) s = smax;

    const int hg = c0 >> 5, hiq = (c0 >> 2) & 1, rq = (c0 & 31) >> 3;
    const int lane = hiq * 32 + l31;

    const float* obase = oparts + ((size_t)b * NSEGk + segbase) * 8192
                       + (size_t)w * 2048 + (size_t)lane * 32 + hg * 16 + rq * 4;
    const float* lbase = lparts + ((size_t)b * NSEGk + segbase) * 128 + w * 32 + l31;

    float4 acc = make_float4(0.f, 0.f, 0.f, 0.f);
    float lsum = 0.f;
    for (int k = 0; k < s; ++k) {
        float4 v = *(const float4*)(obase + (size_t)k * 8192);
        acc.x += v.x; acc.y += v.y; acc.z += v.z; acc.w += v.w;
        lsum += lbase[(size_t)k * 128];
    }
    float inv = 1.0f / lsum;
    acc.x *= inv; acc.y *= inv; acc.z *= inv; acc.w *= inv;
    *(float4*)(out + (size_t)row * HD + c0) = acc;
}

// ---------------------------------------------------------------------------
extern "C" void kernel_launch(void* const* d_in, const int* in_sizes, int n_in,
                              void* d_out, int out_size, void* d_ws, size_t ws_size,
                              hipStream_t stream)
{
    const float* x  = (const float*)d_in[0];
    const float* Wq = (const float*)d_in[1];
    const float* Wk = (const float*)d_in[2];
    const float* Wv = (const float*)d_in[3];

    const size_t nrows = (size_t)NB * TSEQ;

    // Choose split depth from workspace budget. smax=8 (v5-proven): 800
    // blocks, 26 MB partials.
    const size_t fixed_bytes = 3 * nrows * HD * 2 + (size_t)3 * HD * WK * 2;
    int smax = 1, NSEG = 32;
    const int cands[3] = {8, 4, 2};
    for (int i = 0; i < 3; ++i) {
        int sm = cands[i], ns = 0;
        for (int q = 0; q < 32; ++q) {
            int sg = (q + 2) >> 1;
            if (sg > sm) sg = sm;
            ns += sg;
        }
        size_t need = fixed_bytes + (size_t)NB * ns * (8192 + 128) * 4;
        if (need <= ws_size) { smax = sm; NSEG = ns; break; }
    }

    short* qg  = (short*)d_ws;                 // bf16 [nrows][64]   2 MB
    short* kg  = qg + nrows * HD;              // bf16 [nrows][64]   2 MB
    short* vtg = kg + nrows * HD;              // bf16 [NB][64][T]   2 MB
    short* Wt  = vtg + nrows * HD;             // bf16 [3][64][224]  84 KB
    float* oparts = (float*)(Wt + 3 * HD * WK);// fp32 [NB][NSEG][8192]
    float* lparts = oparts + (size_t)NB * NSEG * 8192; // fp32 [NB][NSEG][128]
    float* outp = (float*)d_out;

    prep_kernel<<<dim3(168), dim3(256), 0, stream>>>(Wq, Wk, Wv, Wt);
    qkv_mfma_kernel<<<dim3(512), dim3(192), 0, stream>>>(x, Wt, qg, kg, vtg);
    flash_mfma_kernel<<<dim3(NSEG, NB), dim3(256), 0, stream>>>(qg, kg, vtg,
                                                               oparts, lparts,
                                                               NSEG, smax);
    finalize_kernel<<<dim3(1024), dim3(256), 0, stream>>>(oparts, lparts, outp,
                                                          NSEG, smax);
}

// Round 12
// 106.793 us; speedup vs baseline: 2.8626x; 1.0307x over previous
//
#include <hip/hip_runtime.h>

// B=4, T=4096, E=204, H=64, fp32 in/out. Causal single-head attention.
#define TSEQ   4096
#define NB     4
#define EMB    204
#define HD     64
#define WK     224    // padded K dim for projection (204 -> 7*32)
#define XSTR   232    // x LDS row stride (shorts)
#define KTILE  64     // keys per flash tile

typedef __attribute__((ext_vector_type(8))) short bf16x8;
typedef __attribute__((ext_vector_type(4))) float f32x4;
typedef __attribute__((ext_vector_type(16))) float f32x16;
typedef __attribute__((ext_vector_type(4))) unsigned u32x4;

__device__ __forceinline__ short f2bf(float f) {
    unsigned u = __float_as_uint(f);
    return (short)((u + 0x7fffu + ((u >> 16) & 1u)) >> 16);  // RNE
}
__device__ __forceinline__ float bf2f(unsigned h16) {
    return __uint_as_float(h16 << 16);
}

// ---------------------------------------------------------------------------
// Prep: W transpose->bf16 (Wt [3][64][224]).
// ---------------------------------------------------------------------------
__global__ __launch_bounds__(256) void prep_kernel(
    const float* __restrict__ Wq,
    const float* __restrict__ Wk,
    const float* __restrict__ Wv,
    short* __restrict__ Wt)
{
    int f = blockIdx.x * 256 + threadIdx.x;
    if (f < 3 * HD * WK) {
        int e   = f % WK;
        int h   = (f / WK) % HD;
        int mat = f / (WK * HD);
        const float* W = (mat == 0) ? Wq : (mat == 1) ? Wk : Wv;
        float v = (e < EMB) ? W[e * HD + h] : 0.f;
        Wt[f] = f2bf(v);
    }
}

// ---------------------------------------------------------------------------
// QKV projection: 512 blocks x 192 thr (3 waves). Block = 32 x-rows.
// Wave w computes matrix w (56 MFMA over 2 16-row tiles). q is PRE-SCALED
// by log2(e)/sqrt(204) for exp2 in flash.
// q,k -> [row][64] bf16; v -> vT [b][hd][4096] bf16.
// ---------------------------------------------------------------------------
__global__ __launch_bounds__(192) void qkv_mfma_kernel(
    const float* __restrict__ x,
    const short* __restrict__ Wt,
    short* __restrict__ qg,
    short* __restrict__ kg,
    short* __restrict__ vtg)
{
    __shared__ __align__(16) short xs[32 * XSTR];   // 14848 B

    const int t    = threadIdx.x;
    const int lane = t & 63;
    const int w    = t >> 6;          // 0..2 = matrix id
    const int l15  = lane & 15;
    const int quad = lane >> 4;
    const long long rowb = (long long)blockIdx.x * 32;

    for (int c = t; c < 1632; c += 192) {
        int r = c / 51, c4 = c % 51;
        float4 xv = *(const float4*)(x + (rowb + r) * EMB + c4 * 4);
        unsigned p0 = (unsigned)(unsigned short)f2bf(xv.x)
                    | ((unsigned)(unsigned short)f2bf(xv.y) << 16);
        unsigned p1 = (unsigned)(unsigned short)f2bf(xv.z)
                    | ((unsigned)(unsigned short)f2bf(xv.w) << 16);
        uint2 pk; pk.x = p0; pk.y = p1;
        *(uint2*)(&xs[r * XSTR + c4 * 4]) = pk;
    }
    for (int c = t; c < 32 * 28; c += 192) {       // zero pad cols 204..231
        int r = c / 28, cc = c % 28;
        xs[r * XSTR + EMB + cc] = 0;
    }
    __syncthreads();

    f32x4 acc[2][4];
#pragma unroll
    for (int rt = 0; rt < 2; ++rt)
#pragma unroll
        for (int nt = 0; nt < 4; ++nt) acc[rt][nt] = (f32x4){0.f, 0.f, 0.f, 0.f};

    const short* Wb = Wt + (size_t)w * HD * WK;
#pragma unroll
    for (int ks = 0; ks < 7; ++ks) {
        bf16x8 af[2];
#pragma unroll
        for (int rt = 0; rt < 2; ++rt)
            af[rt] = *(const bf16x8*)(&xs[(rt * 16 + l15) * XSTR + ks * 32 + quad * 8]);
#pragma unroll
        for (int nt = 0; nt < 4; ++nt) {
            bf16x8 bfr = *(const bf16x8*)(Wb + (size_t)(nt * 16 + l15) * WK
                                          + ks * 32 + quad * 8);
#pragma unroll
            for (int rt = 0; rt < 2; ++rt)
                acc[rt][nt] = __builtin_amdgcn_mfma_f32_16x16x32_bf16(af[rt], bfr, acc[rt][nt], 0, 0, 0);
        }
    }

    // scale = log2(e) / sqrt(204), folded into q (flash uses exp2)
    const float scale = 0.101008857f;
#pragma unroll
    for (int rt = 0; rt < 2; ++rt) {
        if (w == 0) {
#pragma unroll
            for (int r = 0; r < 4; ++r) {
                long long grow = rowb + rt * 16 + quad * 4 + r;
#pragma unroll
                for (int nt = 0; nt < 4; ++nt)
                    qg[grow * HD + nt * 16 + l15] = f2bf(acc[rt][nt][r] * scale);
            }
        } else if (w == 1) {
#pragma unroll
            for (int r = 0; r < 4; ++r) {
                long long grow = rowb + rt * 16 + quad * 4 + r;
#pragma unroll
                for (int nt = 0; nt < 4; ++nt)
                    kg[grow * HD + nt * 16 + l15] = f2bf(acc[rt][nt][r]);
            }
        } else {
#pragma unroll
            for (int r = 0; r < 4; ++r) {
                long long grow = rowb + rt * 16 + quad * 4 + r;
                int bb = (int)(grow >> 12);
                int tt = (int)(grow & 4095);
#pragma unroll
                for (int nt = 0; nt < 4; ++nt)
                    vtg[((long long)bb * HD + nt * 16 + l15) * TSEQ + tt] = f2bf(acc[rt][nt][r]);
            }
        }
    }
}

// ---------------------------------------------------------------------------
// Flash attention: v5 core FROZEN (every structural change regressed:
// v6 VGPR cap -> spills; v7 smax=16 -> partial traffic; v9 fused fixup ->
// fence/L2-writeback). v11 change is epilogue-dtype only: O-partials are
// stored as BF16 (halves the measured 0.33us/MB split-K round-trip);
// l partials stay fp32; finalize sums in fp32.
//
// Core: swapped-operand 32x32x16 MFMA (S^T = K Q^T: C layout col=lane&31,
// row=(r&3)+8*(r>>2)+4*hi), in-register softmax via exp2 (q pre-scaled by
// log2e) + v_cvt_pk_bf16_f32 + v_permlane32_swap_b32 -> PV B-frags, zero
// P-LDS; K/V double-buffered global_load_lds (linear LDS dest, XOR-swizzled
// per-lane global src, same XOR on read -> conflict-free ds_read_b128);
// 1 barrier/tile; smax=8 stream-K; partials to private segments; NO atomics.
// ---------------------------------------------------------------------------
__global__ __launch_bounds__(256, 4) void flash_mfma_kernel(
    const short* __restrict__ qg,    // bf16 [NB*T][64], pre-scaled
    const short* __restrict__ kg,    // bf16 [NB*T][64]
    const short* __restrict__ vtg,   // bf16 [NB][64][T]
    short* __restrict__ oparts,      // bf16 [NB][NSEG][8192]
    float* __restrict__ lparts,      // fp32 [NB][NSEG][128]
    int NSEGk, int smax)
{
    __shared__ __align__(16) short Ks[2][KTILE * HD];   // 2 x 8 KB, linear
    __shared__ __align__(16) short Vt[2][HD * KTILE];   // 2 x 8 KB, linear

    const int t    = threadIdx.x;
    const int lane = t & 63;
    const int w    = t >> 6;
    const int l31  = lane & 31;
    const int hi   = lane >> 5;
    const int wq   = w * 32;              // wave's q-row offset in block

    const int b = blockIdx.y;
    const int p = NSEGk - 1 - (int)blockIdx.x;  // biggest qt3 dispatched first

    // Decode p -> (qt3, split): s(qt3) = min(smax,(qt3+2)>>1), prefix walk.
    int qt3 = 0, base = 0;
    for (;; ++qt3) {
        int sg = (qt3 + 2) >> 1;
        if (sg > smax) sg = smax;
        if (p < base + sg) break;
        base += sg;
    }
    int s = (qt3 + 2) >> 1;
    if (s > smax) s = smax;
    const int split  = p - base;
    const int ntiles = 2 * qt3 + 2;
    const int chunk  = (ntiles + s - 1) / s;
    const int kt0    = split * chunk;
    const int kt1    = min(ntiles, kt0 + chunk);

    const int qbase = qt3 * 128;
    const long long rowb = (long long)b * TSEQ;
    const int qA = qbase + wq + l31;      // this lane's q row (within batch)

    // Q B-fragments (pre-scaled): aq[c] = qg[qA][c*16 + hi*8 .. +7]
    bf16x8 aq[4];
#pragma unroll
    for (int c = 0; c < 4; ++c)
        aq[c] = *(const bf16x8*)(qg + (rowb + qA) * HD + c * 16 + hi * 8);

    f32x16 Oacc[2];
#pragma unroll
    for (int hg = 0; hg < 2; ++hg)
#pragma unroll
        for (int r = 0; r < 16; ++r) Oacc[hg][r] = 0.f;
    float lsum = 0.f;

    // Async stage of tile KT into buffer BUF. Each wave issues 2 K + 2 V
    // global_load_lds (1 KB each: 8 rows x 128 B). LDS dest linear; global
    // src chunk = lds_chunk ^ (row&7)  (both tiles are 64 rows x 8 chunks).
#define STAGE(BUF, KT) do {                                                   \
        const int k0s = (KT) * KTILE;                                         \
        _Pragma("unroll")                                                     \
        for (int j = 0; j < 2; ++j) {                                         \
            const int rr = (w * 2 + j) * 8 + (lane >> 3);                     \
            const int cc = (lane & 7) ^ (rr & 7);                             \
            const short* srcK = kg + (rowb + k0s + rr) * HD + cc * 8;         \
            __builtin_amdgcn_global_load_lds(                                 \
                (const __attribute__((address_space(1))) void*)srcK,          \
                (__attribute__((address_space(3))) void*)&Ks[BUF][(w * 2 + j) * 512], \
                16, 0, 0);                                                    \
            const short* srcV = vtg + ((long long)b * HD + rr) * TSEQ + k0s + cc * 8; \
            __builtin_amdgcn_global_load_lds(                                 \
                (const __attribute__((address_space(1))) void*)srcV,          \
                (__attribute__((address_space(3))) void*)&Vt[BUF][(w * 2 + j) * 512], \
                16, 0, 0);                                                    \
        }                                                                     \
    } while (0)

    int cur = 0;
    STAGE(0, kt0);
    __syncthreads();   // drain staging (vmcnt) + sync

    for (int kt = kt0; kt < kt1; ++kt) {
        const int k0 = kt * KTILE;
        if (kt + 1 < kt1) STAGE(cur ^ 1, kt + 1);   // async prefetch next

        const short* ksb = Ks[cur];
        const short* vsb = Vt[cur];
        const bool act  = (k0 <= qbase + wq + 31);  // wave has allowed keys
        const bool full = (k0 + 63 <= qbase + wq);  // no masking needed

        if (act) {
            // ---- S^T = K Q^T, then in-register softmax -> packed P^T ----
            unsigned cd[2][8];
#pragma unroll
            for (int kg2 = 0; kg2 < 2; ++kg2) {
                f32x16 S;
#pragma unroll
                for (int r = 0; r < 16; ++r) S[r] = 0.f;
#pragma unroll
                for (int c = 0; c < 4; ++c) {
                    bf16x8 kf = *(const bf16x8*)(ksb + (kg2 * 32 + l31) * HD
                                   + (((2 * c + hi) ^ (l31 & 7)) * 8));
                    S = __builtin_amdgcn_mfma_f32_32x32x16_bf16(kf, aq[c], S, 0, 0, 0);
                }
                const int jb = k0 + kg2 * 32 + 4 * hi;   // key base for this lane
#pragma unroll
                for (int g = 0; g < 8; ++g) {
                    float e0 = __builtin_amdgcn_exp2f(S[2 * g]);
                    float e1 = __builtin_amdgcn_exp2f(S[2 * g + 1]);
                    if (!full) {
                        const int j0 = jb + 8 * (g >> 1) + 2 * (g & 1);
                        if (j0     > qA) e0 = 0.f;
                        if (j0 + 1 > qA) e1 = 0.f;
                    }
                    lsum += e0 + e1;
                    asm("v_cvt_pk_bf16_f32 %0, %1, %2"
                        : "=v"(cd[kg2][g]) : "v"(e0), "v"(e1));
                }
            }

            // ---- O^T += V^T P^T : permlane32_swap builds P^T B-frags ----
#pragma unroll
            for (int kc = 0; kc < 4; ++kc) {
                unsigned u0 = cd[kc >> 1][4 * (kc & 1) + 0];
                unsigned u1 = cd[kc >> 1][4 * (kc & 1) + 1];
                unsigned u2 = cd[kc >> 1][4 * (kc & 1) + 2];
                unsigned u3 = cd[kc >> 1][4 * (kc & 1) + 3];
                asm("v_permlane32_swap_b32 %0, %1" : "+v"(u0), "+v"(u2));
                asm("v_permlane32_swap_b32 %0, %1" : "+v"(u1), "+v"(u3));
                u32x4 pk = {u0, u1, u2, u3};
                bf16x8 pb = __builtin_bit_cast(bf16x8, pk);
#pragma unroll
                for (int hg = 0; hg < 2; ++hg) {
                    bf16x8 vf = *(const bf16x8*)(vsb + (hg * 32 + l31) * HD
                                   + (((2 * kc + hi) ^ (l31 & 7)) * 8));
                    Oacc[hg] = __builtin_amdgcn_mfma_f32_32x32x16_bf16(vf, pb, Oacc[hg], 0, 0, 0);
                }
            }
        }

        __syncthreads();   // staging of next tile complete; all reads done
        cur ^= 1;
    }

    // ---- Epilogue: stream partial O (bf16) + l (fp32) to private segment.
    // Layout (shorts): oparts[b][p][w*2048 + lane*32 + hg*16 + r].
    short* optr = oparts + ((size_t)b * NSEGk + p) * 8192
                + (size_t)w * 2048 + (size_t)lane * 32;
#pragma unroll
    for (int hg = 0; hg < 2; ++hg) {
        uint2 pk0, pk1;
        asm("v_cvt_pk_bf16_f32 %0, %1, %2" : "=v"(pk0.x) : "v"(Oacc[hg][0]), "v"(Oacc[hg][1]));
        asm("v_cvt_pk_bf16_f32 %0, %1, %2" : "=v"(pk0.y) : "v"(Oacc[hg][2]), "v"(Oacc[hg][3]));
        asm("v_cvt_pk_bf16_f32 %0, %1, %2" : "=v"(pk1.x) : "v"(Oacc[hg][4]), "v"(Oacc[hg][5]));
        asm("v_cvt_pk_bf16_f32 %0, %1, %2" : "=v"(pk1.y) : "v"(Oacc[hg][6]), "v"(Oacc[hg][7]));
        *(uint2*)(optr + hg * 16)     = pk0;
        *(uint2*)(optr + hg * 16 + 4) = pk1;
        asm("v_cvt_pk_bf16_f32 %0, %1, %2" : "=v"(pk0.x) : "v"(Oacc[hg][8]),  "v"(Oacc[hg][9]));
        asm("v_cvt_pk_bf16_f32 %0, %1, %2" : "=v"(pk0.y) : "v"(Oacc[hg][10]), "v"(Oacc[hg][11]));
        asm("v_cvt_pk_bf16_f32 %0, %1, %2" : "=v"(pk1.x) : "v"(Oacc[hg][12]), "v"(Oacc[hg][13]));
        asm("v_cvt_pk_bf16_f32 %0, %1, %2" : "=v"(pk1.y) : "v"(Oacc[hg][14]), "v"(Oacc[hg][15]));
        *(uint2*)(optr + hg * 16 + 8)  = pk0;
        *(uint2*)(optr + hg * 16 + 12) = pk1;
    }

    lsum += __shfl_xor(lsum, 32, 64);
    if (hi == 0)
        lparts[((size_t)b * NSEGk + p) * 128 + w * 32 + l31] = lsum;
#undef STAGE
}

// ---------------------------------------------------------------------------
// Finalize: out[row][col] = sum_s opart(bf16) / sum_s lpart. fp32 accum.
// 1024 x 256, 16 rows/block; each thread owns 4 consecutive cols.
// ---------------------------------------------------------------------------
__global__ __launch_bounds__(256) void finalize_kernel(
    const short* __restrict__ oparts,
    const float* __restrict__ lparts,
    float* __restrict__ out,
    int NSEGk, int smax)
{
    const int row = blockIdx.x * 16 + (threadIdx.x >> 4);
    const int c0  = (threadIdx.x & 15) * 4;
    const int b = row >> 12, rowin = row & 4095;
    const int qt3 = rowin >> 7, w = (rowin >> 5) & 3, l31 = rowin & 31;

    int segbase = 0;
    for (int j = 0; j < qt3; ++j) {
        int sg = (j + 2) >> 1;
        if (sg > smax) sg = smax;
        segbase += sg;
    }
    int s = (qt3 + 2) >> 1;
    if (s > smax) s = smax;

    const int hg = c0 >> 5, hiq = (c0 >> 2) & 1, rq = (c0 & 31) >> 3;
    const int lane = hiq * 32 + l31;

    const short* obase = oparts + ((size_t)b * NSEGk + segbase) * 8192
                       + (size_t)w * 2048 + (size_t)lane * 32 + hg * 16 + rq * 4;
    const float* lbase = lparts + ((size_t)b * NSEGk + segbase) * 128 + w * 32 + l31;

    float4 acc = make_float4(0.f, 0.f, 0.f, 0.f);
    float lsum = 0.f;
    for (int k = 0; k < s; ++k) {
        uint2 u = *(const uint2*)(obase + (size_t)k * 8192);
        acc.x += bf2f(u.x & 0xffffu);
        acc.y += bf2f(u.x >> 16);
        acc.z += bf2f(u.y & 0xffffu);
        acc.w += bf2f(u.y >> 16);
        lsum += lbase[(size_t)k * 128];
    }
    float inv = 1.0f / lsum;
    acc.x *= inv; acc.y *= inv; acc.z *= inv; acc.w *= inv;
    *(float4*)(out + (size_t)row * HD + c0) = acc;
}

// ---------------------------------------------------------------------------
extern "C" void kernel_launch(void* const* d_in, const int* in_sizes, int n_in,
                              void* d_out, int out_size, void* d_ws, size_t ws_size,
                              hipStream_t stream)
{
    const float* x  = (const float*)d_in[0];
    const float* Wq = (const float*)d_in[1];
    const float* Wk = (const float*)d_in[2];
    const float* Wv = (const float*)d_in[3];

    const size_t nrows = (size_t)NB * TSEQ;

    // Split depth from workspace budget. smax=8 (proven): 800 blocks,
    // 12.8 MB bf16 partials (halved from fp32).
    const size_t fixed_bytes = 3 * nrows * HD * 2 + (size_t)3 * HD * WK * 2;
    int smax = 1, NSEG = 32;
    const int cands[3] = {8, 4, 2};
    for (int i = 0; i < 3; ++i) {
        int sm = cands[i], ns = 0;
        for (int q = 0; q < 32; ++q) {
            int sg = (q + 2) >> 1;
            if (sg > sm) sg = sm;
            ns += sg;
        }
        size_t need = fixed_bytes + (size_t)NB * ns * (8192 * 2 + 128 * 4);
        if (need <= ws_size) { smax = sm; NSEG = ns; break; }
    }

    short* qg  = (short*)d_ws;                 // bf16 [nrows][64]   2 MB
    short* kg  = qg + nrows * HD;              // bf16 [nrows][64]   2 MB
    short* vtg = kg + nrows * HD;              // bf16 [NB][64][T]   2 MB
    short* Wt  = vtg + nrows * HD;             // bf16 [3][64][224]  84 KB
    short* oparts = Wt + 3 * HD * WK;          // bf16 [NB][NSEG][8192]
    float* lparts = (float*)(oparts + (size_t)NB * NSEG * 8192); // fp32
    float* outp = (float*)d_out;

    prep_kernel<<<dim3(168), dim3(256), 0, stream>>>(Wq, Wk, Wv, Wt);
    qkv_mfma_kernel<<<dim3(512), dim3(192), 0, stream>>>(x, Wt, qg, kg, vtg);
    flash_mfma_kernel<<<dim3(NSEG, NB), dim3(256), 0, stream>>>(qg, kg, vtg,
                                                               oparts, lparts,
                                                               NSEG, smax);
    finalize_kernel<<<dim3(1024), dim3(256), 0, stream>>>(oparts, lparts, outp,
                                                          NSEG, smax);
}

// Round 13
// 106.313 us; speedup vs baseline: 2.8756x; 1.0045x over previous
//
#include <hip/hip_runtime.h>

// B=4, T=4096, E=204, H=64, fp32 in/out. Causal single-head attention.
#define TSEQ   4096
#define NB     4
#define EMB    204
#define HD     64
#define WK     224    // padded K dim for projection (204 -> 7*32)
#define XSTR   232    // x LDS row stride (shorts)
#define KTILE  64     // keys per flash tile

typedef __attribute__((ext_vector_type(8))) short bf16x8;
typedef __attribute__((ext_vector_type(4))) float f32x4;
typedef __attribute__((ext_vector_type(16))) float f32x16;
typedef __attribute__((ext_vector_type(4))) unsigned u32x4;

__device__ __forceinline__ short f2bf(float f) {
    unsigned u = __float_as_uint(f);
    return (short)((u + 0x7fffu + ((u >> 16) & 1u)) >> 16);  // RNE
}
__device__ __forceinline__ float bf2f(unsigned h16) {
    return __uint_as_float(h16 << 16);
}

// ---------------------------------------------------------------------------
// Prep: W transpose->bf16 (Wt [3][64][224]).
// ---------------------------------------------------------------------------
__global__ __launch_bounds__(256) void prep_kernel(
    const float* __restrict__ Wq,
    const float* __restrict__ Wk,
    const float* __restrict__ Wv,
    short* __restrict__ Wt)
{
    int f = blockIdx.x * 256 + threadIdx.x;
    if (f < 3 * HD * WK) {
        int e   = f % WK;
        int h   = (f / WK) % HD;
        int mat = f / (WK * HD);
        const float* W = (mat == 0) ? Wq : (mat == 1) ? Wk : Wv;
        float v = (e < EMB) ? W[e * HD + h] : 0.f;
        Wt[f] = f2bf(v);
    }
}

// ---------------------------------------------------------------------------
// QKV projection: 512 blocks x 192 thr (3 waves). Block = 32 x-rows.
// Wave w computes matrix w (56 MFMA over 2 16-row tiles). q is PRE-SCALED
// by log2(e)/sqrt(204) for exp2 in flash.
// q,k -> [row][64] bf16; v -> vT [b][hd][4096] bf16.
// ---------------------------------------------------------------------------
__global__ __launch_bounds__(192) void qkv_mfma_kernel(
    const float* __restrict__ x,
    const short* __restrict__ Wt,
    short* __restrict__ qg,
    short* __restrict__ kg,
    short* __restrict__ vtg)
{
    __shared__ __align__(16) short xs[32 * XSTR];   // 14848 B

    const int t    = threadIdx.x;
    const int lane = t & 63;
    const int w    = t >> 6;          // 0..2 = matrix id
    const int l15  = lane & 15;
    const int quad = lane >> 4;
    const long long rowb = (long long)blockIdx.x * 32;

    for (int c = t; c < 1632; c += 192) {
        int r = c / 51, c4 = c % 51;
        float4 xv = *(const float4*)(x + (rowb + r) * EMB + c4 * 4);
        unsigned p0 = (unsigned)(unsigned short)f2bf(xv.x)
                    | ((unsigned)(unsigned short)f2bf(xv.y) << 16);
        unsigned p1 = (unsigned)(unsigned short)f2bf(xv.z)
                    | ((unsigned)(unsigned short)f2bf(xv.w) << 16);
        uint2 pk; pk.x = p0; pk.y = p1;
        *(uint2*)(&xs[r * XSTR + c4 * 4]) = pk;
    }
    for (int c = t; c < 32 * 28; c += 192) {       // zero pad cols 204..231
        int r = c / 28, cc = c % 28;
        xs[r * XSTR + EMB + cc] = 0;
    }
    __syncthreads();

    f32x4 acc[2][4];
#pragma unroll
    for (int rt = 0; rt < 2; ++rt)
#pragma unroll
        for (int nt = 0; nt < 4; ++nt) acc[rt][nt] = (f32x4){0.f, 0.f, 0.f, 0.f};

    const short* Wb = Wt + (size_t)w * HD * WK;
#pragma unroll
    for (int ks = 0; ks < 7; ++ks) {
        bf16x8 af[2];
#pragma unroll
        for (int rt = 0; rt < 2; ++rt)
            af[rt] = *(const bf16x8*)(&xs[(rt * 16 + l15) * XSTR + ks * 32 + quad * 8]);
#pragma unroll
        for (int nt = 0; nt < 4; ++nt) {
            bf16x8 bfr = *(const bf16x8*)(Wb + (size_t)(nt * 16 + l15) * WK
                                          + ks * 32 + quad * 8);
#pragma unroll
            for (int rt = 0; rt < 2; ++rt)
                acc[rt][nt] = __builtin_amdgcn_mfma_f32_16x16x32_bf16(af[rt], bfr, acc[rt][nt], 0, 0, 0);
        }
    }

    // scale = log2(e) / sqrt(204), folded into q (flash uses exp2)
    const float scale = 0.101008857f;
#pragma unroll
    for (int rt = 0; rt < 2; ++rt) {
        if (w == 0) {
#pragma unroll
            for (int r = 0; r < 4; ++r) {
                long long grow = rowb + rt * 16 + quad * 4 + r;
#pragma unroll
                for (int nt = 0; nt < 4; ++nt)
                    qg[grow * HD + nt * 16 + l15] = f2bf(acc[rt][nt][r] * scale);
            }
        } else if (w == 1) {
#pragma unroll
            for (int r = 0; r < 4; ++r) {
                long long grow = rowb + rt * 16 + quad * 4 + r;
#pragma unroll
                for (int nt = 0; nt < 4; ++nt)
                    kg[grow * HD + nt * 16 + l15] = f2bf(acc[rt][nt][r]);
            }
        } else {
#pragma unroll
            for (int r = 0; r < 4; ++r) {
                long long grow = rowb + rt * 16 + quad * 4 + r;
                int bb = (int)(grow >> 12);
                int tt = (int)(grow & 4095);
#pragma unroll
                for (int nt = 0; nt < 4; ++nt)
                    vtg[((long long)bb * HD + nt * 16 + l15) * TSEQ + tt] = f2bf(acc[rt][nt][r]);
            }
        }
    }
}

// ---------------------------------------------------------------------------
// Flash attention v12 = v11 core with T4 counted-vmcnt pipeline.
// v11's __syncthreads per tile drained vmcnt(0) -> the just-issued prefetch
// serialized with compute (per-tile ~4200cy, ~400cy useful). Now:
//   prologue: STAGE(kt0), STAGE(kt0+1)
//   loop:  s_waitcnt vmcnt(4|0)  (this tile's 4 loads only; next stays
//          in flight) -> s_barrier -> compute -> s_barrier -> STAGE(kt+2)
// sched_barrier(0) fences stop the scheduler hoisting dependent ds_reads
// above the wait (rule #18). Barriers wave-uniform (guards only on STAGE).
// Everything else byte-identical v11 (bf16 O-partials, smax=8, no atomics).
// ---------------------------------------------------------------------------
__global__ __launch_bounds__(256, 4) void flash_mfma_kernel(
    const short* __restrict__ qg,    // bf16 [NB*T][64], pre-scaled
    const short* __restrict__ kg,    // bf16 [NB*T][64]
    const short* __restrict__ vtg,   // bf16 [NB][64][T]
    short* __restrict__ oparts,      // bf16 [NB][NSEG][8192]
    float* __restrict__ lparts,      // fp32 [NB][NSEG][128]
    int NSEGk, int smax)
{
    __shared__ __align__(16) short Ks[2][KTILE * HD];   // 2 x 8 KB, linear
    __shared__ __align__(16) short Vt[2][HD * KTILE];   // 2 x 8 KB, linear

    const int t    = threadIdx.x;
    const int lane = t & 63;
    const int w    = t >> 6;
    const int l31  = lane & 31;
    const int hi   = lane >> 5;
    const int wq   = w * 32;              // wave's q-row offset in block

    const int b = blockIdx.y;
    const int p = NSEGk - 1 - (int)blockIdx.x;  // biggest qt3 dispatched first

    // Decode p -> (qt3, split): s(qt3) = min(smax,(qt3+2)>>1), prefix walk.
    int qt3 = 0, base = 0;
    for (;; ++qt3) {
        int sg = (qt3 + 2) >> 1;
        if (sg > smax) sg = smax;
        if (p < base + sg) break;
        base += sg;
    }
    int s = (qt3 + 2) >> 1;
    if (s > smax) s = smax;
    const int split  = p - base;
    const int ntiles = 2 * qt3 + 2;
    const int chunk  = (ntiles + s - 1) / s;
    const int kt0    = split * chunk;
    const int kt1    = min(ntiles, kt0 + chunk);

    const int qbase = qt3 * 128;
    const long long rowb = (long long)b * TSEQ;
    const int qA = qbase + wq + l31;      // this lane's q row (within batch)

    // Q B-fragments (pre-scaled): aq[c] = qg[qA][c*16 + hi*8 .. +7]
    bf16x8 aq[4];
#pragma unroll
    for (int c = 0; c < 4; ++c)
        aq[c] = *(const bf16x8*)(qg + (rowb + qA) * HD + c * 16 + hi * 8);

    f32x16 Oacc[2];
#pragma unroll
    for (int hg = 0; hg < 2; ++hg)
#pragma unroll
        for (int r = 0; r < 16; ++r) Oacc[hg][r] = 0.f;
    float lsum = 0.f;

    // Async stage of tile KT into buffer BUF: 4 global_load_lds per wave
    // (2 K + 2 V, 1 KB each). LDS dest linear; global src chunk XOR-swizzled.
#define STAGE(BUF, KT) do {                                                   \
        const int k0s = (KT) * KTILE;                                         \
        _Pragma("unroll")                                                     \
        for (int j = 0; j < 2; ++j) {                                         \
            const int rr = (w * 2 + j) * 8 + (lane >> 3);                     \
            const int cc = (lane & 7) ^ (rr & 7);                             \
            const short* srcK = kg + (rowb + k0s + rr) * HD + cc * 8;         \
            __builtin_amdgcn_global_load_lds(                                 \
                (const __attribute__((address_space(1))) void*)srcK,          \
                (__attribute__((address_space(3))) void*)&Ks[BUF][(w * 2 + j) * 512], \
                16, 0, 0);                                                    \
            const short* srcV = vtg + ((long long)b * HD + rr) * TSEQ + k0s + cc * 8; \
            __builtin_amdgcn_global_load_lds(                                 \
                (const __attribute__((address_space(1))) void*)srcV,          \
                (__attribute__((address_space(3))) void*)&Vt[BUF][(w * 2 + j) * 512], \
                16, 0, 0);                                                    \
        }                                                                     \
    } while (0)

    STAGE(0, kt0);
    if (kt0 + 1 < kt1) STAGE(1, kt0 + 1);

    for (int kt = kt0; kt < kt1; ++kt) {
        const int cur = (kt - kt0) & 1;
        const int k0 = kt * KTILE;

        // Wait for THIS tile's 4 loads only; next tile's stay in flight.
        if (kt + 1 < kt1) asm volatile("s_waitcnt vmcnt(4)" ::: "memory");
        else              asm volatile("s_waitcnt vmcnt(0)" ::: "memory");
        __builtin_amdgcn_sched_barrier(0);
        __builtin_amdgcn_s_barrier();        // all waves' tile-kt loads done
        __builtin_amdgcn_sched_barrier(0);

        const short* ksb = Ks[cur];
        const short* vsb = Vt[cur];
        const bool act  = (k0 <= qbase + wq + 31);  // wave has allowed keys
        const bool full = (k0 + 63 <= qbase + wq);  // no masking needed

        if (act) {
            // ---- S^T = K Q^T, then in-register softmax -> packed P^T ----
            unsigned cd[2][8];
#pragma unroll
            for (int kg2 = 0; kg2 < 2; ++kg2) {
                f32x16 S;
#pragma unroll
                for (int r = 0; r < 16; ++r) S[r] = 0.f;
#pragma unroll
                for (int c = 0; c < 4; ++c) {
                    bf16x8 kf = *(const bf16x8*)(ksb + (kg2 * 32 + l31) * HD
                                   + (((2 * c + hi) ^ (l31 & 7)) * 8));
                    S = __builtin_amdgcn_mfma_f32_32x32x16_bf16(kf, aq[c], S, 0, 0, 0);
                }
                const int jb = k0 + kg2 * 32 + 4 * hi;   // key base for this lane
#pragma unroll
                for (int g = 0; g < 8; ++g) {
                    float e0 = __builtin_amdgcn_exp2f(S[2 * g]);
                    float e1 = __builtin_amdgcn_exp2f(S[2 * g + 1]);
                    if (!full) {
                        const int j0 = jb + 8 * (g >> 1) + 2 * (g & 1);
                        if (j0     > qA) e0 = 0.f;
                        if (j0 + 1 > qA) e1 = 0.f;
                    }
                    lsum += e0 + e1;
                    asm("v_cvt_pk_bf16_f32 %0, %1, %2"
                        : "=v"(cd[kg2][g]) : "v"(e0), "v"(e1));
                }
            }

            // ---- O^T += V^T P^T : permlane32_swap builds P^T B-frags ----
#pragma unroll
            for (int kc = 0; kc < 4; ++kc) {
                unsigned u0 = cd[kc >> 1][4 * (kc & 1) + 0];
                unsigned u1 = cd[kc >> 1][4 * (kc & 1) + 1];
                unsigned u2 = cd[kc >> 1][4 * (kc & 1) + 2];
                unsigned u3 = cd[kc >> 1][4 * (kc & 1) + 3];
                asm("v_permlane32_swap_b32 %0, %1" : "+v"(u0), "+v"(u2));
                asm("v_permlane32_swap_b32 %0, %1" : "+v"(u1), "+v"(u3));
                u32x4 pk = {u0, u1, u2, u3};
                bf16x8 pb = __builtin_bit_cast(bf16x8, pk);
#pragma unroll
                for (int hg = 0; hg < 2; ++hg) {
                    bf16x8 vf = *(const bf16x8*)(vsb + (hg * 32 + l31) * HD
                                   + (((2 * kc + hi) ^ (l31 & 7)) * 8));
                    Oacc[hg] = __builtin_amdgcn_mfma_f32_32x32x16_bf16(vf, pb, Oacc[hg], 0, 0, 0);
                }
            }
        }

        // All waves done reading this buffer before it is restaged.
        __builtin_amdgcn_sched_barrier(0);
        __builtin_amdgcn_s_barrier();
        __builtin_amdgcn_sched_barrier(0);
        if (kt + 2 < kt1) STAGE(cur, kt + 2);
    }

    // ---- Epilogue: stream partial O (bf16) + l (fp32) to private segment.
    short* optr = oparts + ((size_t)b * NSEGk + p) * 8192
                + (size_t)w * 2048 + (size_t)lane * 32;
#pragma unroll
    for (int hg = 0; hg < 2; ++hg) {
        uint2 pk0, pk1;
        asm("v_cvt_pk_bf16_f32 %0, %1, %2" : "=v"(pk0.x) : "v"(Oacc[hg][0]), "v"(Oacc[hg][1]));
        asm("v_cvt_pk_bf16_f32 %0, %1, %2" : "=v"(pk0.y) : "v"(Oacc[hg][2]), "v"(Oacc[hg][3]));
        asm("v_cvt_pk_bf16_f32 %0, %1, %2" : "=v"(pk1.x) : "v"(Oacc[hg][4]), "v"(Oacc[hg][5]));
        asm("v_cvt_pk_bf16_f32 %0, %1, %2" : "=v"(pk1.y) : "v"(Oacc[hg][6]), "v"(Oacc[hg][7]));
        *(uint2*)(optr + hg * 16)     = pk0;
        *(uint2*)(optr + hg * 16 + 4) = pk1;
        asm("v_cvt_pk_bf16_f32 %0, %1, %2" : "=v"(pk0.x) : "v"(Oacc[hg][8]),  "v"(Oacc[hg][9]));
        asm("v_cvt_pk_bf16_f32 %0, %1, %2" : "=v"(pk0.y) : "v"(Oacc[hg][10]), "v"(Oacc[hg][11]));
        asm("v_cvt_pk_bf16_f32 %0, %1, %2" : "=v"(pk1.x) : "v"(Oacc[hg][12]), "v"(Oacc[hg][13]));
        asm("v_cvt_pk_bf16_f32 %0, %1, %2" : "=v"(pk1.y) : "v"(Oacc[hg][14]), "v"(Oacc[hg][15]));
        *(uint2*)(optr + hg * 16 + 8)  = pk0;
        *(uint2*)(optr + hg * 16 + 12) = pk1;
    }

    lsum += __shfl_xor(lsum, 32, 64);
    if (hi == 0)
        lparts[((size_t)b * NSEGk + p) * 128 + w * 32 + l31] = lsum;
#undef STAGE
}

// ---------------------------------------------------------------------------
// Finalize: out[row][col] = sum_s opart(bf16) / sum_s lpart. fp32 accum.
// ---------------------------------------------------------------------------
__global__ __launch_bounds__(256) void finalize_kernel(
    const short* __restrict__ oparts,
    const float* __restrict__ lparts,
    float* __restrict__ out,
    int NSEGk, int smax)
{
    const int row = blockIdx.x * 16 + (threadIdx.x >> 4);
    const int c0  = (threadIdx.x & 15) * 4;
    const int b = row >> 12, rowin = row & 4095;
    const int qt3 = rowin >> 7, w = (rowin >> 5) & 3, l31 = rowin & 31;

    int segbase = 0;
    for (int j = 0; j < qt3; ++j) {
        int sg = (j + 2) >> 1;
        if (sg > smax) sg = smax;
        segbase += sg;
    }
    int s = (qt3 + 2) >> 1;
    if (s > smax) s = smax;

    const int hg = c0 >> 5, hiq = (c0 >> 2) & 1, rq = (c0 & 31) >> 3;
    const int lane = hiq * 32 + l31;

    const short* obase = oparts + ((size_t)b * NSEGk + segbase) * 8192
                       + (size_t)w * 2048 + (size_t)lane * 32 + hg * 16 + rq * 4;
    const float* lbase = lparts + ((size_t)b * NSEGk + segbase) * 128 + w * 32 + l31;

    float4 acc = make_float4(0.f, 0.f, 0.f, 0.f);
    float lsum = 0.f;
    for (int k = 0; k < s; ++k) {
        uint2 u = *(const uint2*)(obase + (size_t)k * 8192);
        acc.x += bf2f(u.x & 0xffffu);
        acc.y += bf2f(u.x >> 16);
        acc.z += bf2f(u.y & 0xffffu);
        acc.w += bf2f(u.y >> 16);
        lsum += lbase[(size_t)k * 128];
    }
    float inv = 1.0f / lsum;
    acc.x *= inv; acc.y *= inv; acc.z *= inv; acc.w *= inv;
    *(float4*)(out + (size_t)row * HD + c0) = acc;
}

// ---------------------------------------------------------------------------
extern "C" void kernel_launch(void* const* d_in, const int* in_sizes, int n_in,
                              void* d_out, int out_size, void* d_ws, size_t ws_size,
                              hipStream_t stream)
{
    const float* x  = (const float*)d_in[0];
    const float* Wq = (const float*)d_in[1];
    const float* Wk = (const float*)d_in[2];
    const float* Wv = (const float*)d_in[3];

    const size_t nrows = (size_t)NB * TSEQ;

    // Split depth from workspace budget. smax=8 (proven): 800 blocks,
    // 12.8 MB bf16 partials.
    const size_t fixed_bytes = 3 * nrows * HD * 2 + (size_t)3 * HD * WK * 2;
    int smax = 1, NSEG = 32;
    const int cands[3] = {8, 4, 2};
    for (int i = 0; i < 3; ++i) {
        int sm = cands[i], ns = 0;
        for (int q = 0; q < 32; ++q) {
            int sg = (q + 2) >> 1;
            if (sg > sm) sg = sm;
            ns += sg;
        }
        size_t need = fixed_bytes + (size_t)NB * ns * (8192 * 2 + 128 * 4);
        if (need <= ws_size) { smax = sm; NSEG = ns; break; }
    }

    short* qg  = (short*)d_ws;                 // bf16 [nrows][64]   2 MB
    short* kg  = qg + nrows * HD;              // bf16 [nrows][64]   2 MB
    short* vtg = kg + nrows * HD;              // bf16 [NB][64][T]   2 MB
    short* Wt  = vtg + nrows * HD;             // bf16 [3][64][224]  84 KB
    short* oparts = Wt + 3 * HD * WK;          // bf16 [NB][NSEG][8192]
    float* lparts = (float*)(oparts + (size_t)NB * NSEG * 8192); // fp32
    float* outp = (float*)d_out;

    prep_kernel<<<dim3(168), dim3(256), 0, stream>>>(Wq, Wk, Wv, Wt);
    qkv_mfma_kernel<<<dim3(512), dim3(192), 0, stream>>>(x, Wt, qg, kg, vtg);
    flash_mfma_kernel<<<dim3(NSEG, NB), dim3(256), 0, stream>>>(qg, kg, vtg,
                                                               oparts, lparts,
                                                               NSEG, smax);
    finalize_kernel<<<dim3(1024), dim3(256), 0, stream>>>(oparts, lparts, outp,
                                                          NSEG, smax);
}